// Round 8
// baseline (2385.964 us; speedup 1.0000x reference)
//
#include <hip/hip_runtime.h>

typedef _Float16 f16x8  __attribute__((ext_vector_type(8)));
typedef float    f32x16 __attribute__((ext_vector_type(16)));

#define TSTEPS 500
#define NB 512
#define LOG2E 1.442695041f

// f64 exp, Cody-Waite reduction + degree-11 Taylor evaluated in ESTRIN form:
// dependency depth 5 FMAs (vs 12 for Horner) — the gate chain is latency-
// bound on wave 0, ~16cy per dependent f64 FMA. Rel err ~1e-15; summation-
// order delta vs Horner ~1e-16/step -> ~4e-11 after 4e5x amplification.
__device__ __forceinline__ double exp_d(double v){
  v = fmin(fmax(v, -700.0), 700.0);
  double t = v * 1.4426950408889634;              // v / ln2
  double nn = rint(t);
  double f = fma(-nn, 6.931471803691238e-01, v);  // LN2_HI
  f = fma(-nn, 1.9082149292705877e-10, f);        // LN2_LO
  double f2 = f*f;
  double f4 = f2*f2;
  double f8 = f4*f4;
  double a0 = 1.0 + f;
  double a1 = fma(f, 1.6666666666666666e-01, 0.5);                       // c3,c2
  double a2 = fma(f, 8.3333333333333332e-03, 4.1666666666666664e-02);    // c5,c4
  double a3 = fma(f, 1.9841269841269841e-04, 1.3888888888888889e-03);    // c7,c6
  double a4 = fma(f, 2.7557319223985893e-06, 2.4801587301587302e-05);    // c9,c8
  double a5 = fma(f, 2.5052108385441718e-08, 2.7557319223985888e-07);    // c11,c10
  double b0 = fma(f2, a1, a0);
  double b1 = fma(f2, a3, a2);
  double b2 = fma(f2, a5, a4);
  double p  = fma(f4, b1, b0);
  p = fma(f8, b2, p);
  long long bits = (1023LL + (long long)nn) << 52;
  return p * __longlong_as_double(bits);
}

// 1/x via v_rcp_f64 + 2 Newton steps (~1e-16 rel err).
__device__ __forceinline__ double rcp_nr(double x){
  double r;
  asm("v_rcp_f64 %0, %1" : "=v"(r) : "v"(x));
  r = fma(fma(-x, r, 1.0), r, r);
  r = fma(fma(-x, r, 1.0), r, r);
  return r;
}

// ---------------------------------------------------------------------------
// Fused GRU, 256 threads (4 waves) per (g,n) sequence.
// R6 structure kept: column-split dots (all waves) -> psh -> wave-0 gates.
//
// R7 changes — stall removal (R6 showed VALUBusy 35% at unchanged wall:
// the kernel is drain/latency-bound, ~1800 cy/step of stalls):
// (1) 4-step SUPERSTEP x prefetch (500 = 4*125): wave 1 issues the next
//     superstep's 4 x-loads at the START of phase A of u=0, so the
//     barrier's compiler-emitted "s_waitcnt vmcnt(0)" drains them with
//     ~500 cy of dot-work cover — ONE partial stall per 4 steps instead
//     of a near-full HBM latency EVERY step (load was issued right
//     before the barrier).
// (2) qkv store delayed one step: h(t-1) stored at start of step t's
//     phase A — store-ack drains under a full phase of cover, not at b2.
// (3) exp_d in Estrin form (dep depth 12 -> 5).
// Keep __launch_bounds__(256,2) (VGPR cap 128; >128 halves residency).
// TRIPWIRE: FETCH > 0.5 GB = prefetch regs spilled -> superstep 2 next.
// (R7 resubmit: previous run died on container acquire — infra, not kernel;
// barriers are uniform, indices clamped, no uninit reads.)
// ---------------------------------------------------------------------------
__global__ __launch_bounds__(256, 2) void gru_f64(
    const float* __restrict__ x,    // [500,512,64] f32
    const float* __restrict__ st,   // [3,512,64] f32
    const float* __restrict__ wih0, const float* __restrict__ whh0,
    const float* __restrict__ bih0, const float* __restrict__ bhh0,
    const float* __restrict__ wih1, const float* __restrict__ whh1,
    const float* __restrict__ bih1, const float* __restrict__ bhh1,
    const float* __restrict__ wih2, const float* __restrict__ whh2,
    const float* __restrict__ bih2, const float* __restrict__ bhh2,
    _Float16* __restrict__ qkv,      // ws: [3,500,512,64] f16
    float* __restrict__ out_state)   // [3,512,64] f32
{
  __shared__ __align__(16) double hsh[72];
  __shared__ __align__(16) double xsh[72];
  __shared__ __align__(16) double psh[4][72];   // r-pre, z-pre, xn, hn per row

  const int tid = threadIdx.x;
  const int j = tid >> 2;            // h-row 0..63 (dot phase)
  const int q = tid & 3;             // column quarter (dot phase)
  const int g = blockIdx.x >> 9;
  const int n = blockIdx.x & 511;

  const float* wih = (g==0) ? wih0 : ((g==1) ? wih1 : wih2);
  const float* whh = (g==0) ? whh0 : ((g==1) ? whh1 : whh2);
  const float* bih = (g==0) ? bih0 : ((g==1) ? bih1 : bih2);
  const float* bhh = (g==0) ? bhh0 : ((g==1) ? bhh1 : bhh2);

  // Weights: rows j(r), 64+j(z), 128+j(n); cols [16q,16q+16). f64 arrays;
  // the allocator remats to f32+cvt under the 128-reg cap (known good).
  double wiR[16], wiZ[16], wiN[16], whR[16], whZ[16], whN[16];
  {
    const float4* pR = (const float4*)(wih + (size_t)(       j)*64 + q*16);
    const float4* pZ = (const float4*)(wih + (size_t)( 64 + j)*64 + q*16);
    const float4* pN = (const float4*)(wih + (size_t)(128 + j)*64 + q*16);
    const float4* rR = (const float4*)(whh + (size_t)(       j)*64 + q*16);
    const float4* rZ = (const float4*)(whh + (size_t)( 64 + j)*64 + q*16);
    const float4* rN = (const float4*)(whh + (size_t)(128 + j)*64 + q*16);
    #pragma unroll
    for (int k=0;k<4;++k){
      float4 a;
      a = pR[k]; wiR[4*k]=(double)a.x; wiR[4*k+1]=(double)a.y; wiR[4*k+2]=(double)a.z; wiR[4*k+3]=(double)a.w;
      a = pZ[k]; wiZ[4*k]=(double)a.x; wiZ[4*k+1]=(double)a.y; wiZ[4*k+2]=(double)a.z; wiZ[4*k+3]=(double)a.w;
      a = pN[k]; wiN[4*k]=(double)a.x; wiN[4*k+1]=(double)a.y; wiN[4*k+2]=(double)a.z; wiN[4*k+3]=(double)a.w;
      a = rR[k]; whR[4*k]=(double)a.x; whR[4*k+1]=(double)a.y; whR[4*k+2]=(double)a.z; whR[4*k+3]=(double)a.w;
      a = rZ[k]; whZ[4*k]=(double)a.x; whZ[4*k+1]=(double)a.y; whZ[4*k+2]=(double)a.z; whZ[4*k+3]=(double)a.w;
      a = rN[k]; whN[4*k]=(double)a.x; whN[4*k+1]=(double)a.y; whN[4*k+2]=(double)a.z; whN[4*k+3]=(double)a.w;
    }
  }
  // Biases folded into accumulator init on q==0 lanes.
  const double bRi  = (q==0) ? ((double)bih[j]    + (double)bhh[j]   ) : 0.0;
  const double bZi  = (q==0) ? ((double)bih[64+j] + (double)bhh[64+j]) : 0.0;
  const double biNi = (q==0) ? (double)bih[128+j] : 0.0;
  const double bhNi = (q==0) ? (double)bhh[128+j] : 0.0;

  const int l2 = tid & 63;
  const float* xp = x + (size_t)n*64 + l2;

  double h = 0.0;                    // live state: wave 0, lane l <-> row l
  // x prefetch: wave 1 lanes hold x[t0+1+u] in xr[u] for the current
  // superstep; xn[u] receives the next superstep's values.
  float xr0=0.f, xr1=0.f, xr2=0.f, xr3=0.f;
  float xn0=0.f, xn1=0.f, xn2=0.f, xn3=0.f;
  if (tid < 64){
    h = (double)st[(size_t)(g*512 + n)*64 + tid];
    hsh[tid + 2*(tid>>4)] = h;
  } else if (tid < 128){
    xsh[l2 + 2*(l2>>4)] = (double)xp[0];
    xr0 = xp[(size_t)1*NB*64];
    xr1 = xp[(size_t)2*NB*64];
    xr2 = xp[(size_t)3*NB*64];
    xr3 = xp[(size_t)4*NB*64];
  }
  _Float16* qout = qkv + ((size_t)g*TSTEPS*NB + n)*64 + tid;  // used by tid<64
  __syncthreads();

  for (int t0 = 0; t0 < TSTEPS; t0 += 4){
    #pragma unroll
    for (int u = 0; u < 4; ++u){
      const int t = t0 + u;

      // delayed qkv store: h(t-1), drains under phase A's cover
      if (tid < 64 && t > 0)
        qout[(size_t)(t-1)*NB*64] = (_Float16)(float)h;

      // batch-issue next superstep's x loads (wave 1, once per superstep)
      if (u == 0 && tid >= 64 && tid < 128){
        int t5 = (t0+5 < TSTEPS) ? (t0+5) : (TSTEPS-1);
        int t6 = (t0+6 < TSTEPS) ? (t0+6) : (TSTEPS-1);
        int t7 = (t0+7 < TSTEPS) ? (t0+7) : (TSTEPS-1);
        int t8 = (t0+8 < TSTEPS) ? (t0+8) : (TSTEPS-1);
        xn0 = xp[(size_t)t5*NB*64];
        xn1 = xp[(size_t)t6*NB*64];
        xn2 = xp[(size_t)t7*NB*64];
        xn3 = xp[(size_t)t8*NB*64];
      }

      // ---- dot phase: all 256 threads ----
      const double2* hp = (const double2*)(&hsh[18*q]);  // 144B-aligned
      const double2* xq = (const double2*)(&xsh[18*q]);

      double hdR=bRi, hdZ=bZi, hdN=bhNi, xdR=0.0, xdZ=0.0, xdN=biNi;
      #pragma unroll
      for (int w=0; w<4; ++w){
        double2 h01 = hp[2*w], h23 = hp[2*w+1];
        double2 x01 = xq[2*w], x23 = xq[2*w+1];
        hdR = fma(whR[4*w+0], h01.x, hdR); hdR = fma(whR[4*w+1], h01.y, hdR);
        hdR = fma(whR[4*w+2], h23.x, hdR); hdR = fma(whR[4*w+3], h23.y, hdR);
        hdZ = fma(whZ[4*w+0], h01.x, hdZ); hdZ = fma(whZ[4*w+1], h01.y, hdZ);
        hdZ = fma(whZ[4*w+2], h23.x, hdZ); hdZ = fma(whZ[4*w+3], h23.y, hdZ);
        hdN = fma(whN[4*w+0], h01.x, hdN); hdN = fma(whN[4*w+1], h01.y, hdN);
        hdN = fma(whN[4*w+2], h23.x, hdN); hdN = fma(whN[4*w+3], h23.y, hdN);
        xdR = fma(wiR[4*w+0], x01.x, xdR); xdR = fma(wiR[4*w+1], x01.y, xdR);
        xdR = fma(wiR[4*w+2], x23.x, xdR); xdR = fma(wiR[4*w+3], x23.y, xdR);
        xdZ = fma(wiZ[4*w+0], x01.x, xdZ); xdZ = fma(wiZ[4*w+1], x01.y, xdZ);
        xdZ = fma(wiZ[4*w+2], x23.x, xdZ); xdZ = fma(wiZ[4*w+3], x23.y, xdZ);
        xdN = fma(wiN[4*w+0], x01.x, xdN); xdN = fma(wiN[4*w+1], x01.y, xdN);
        xdN = fma(wiN[4*w+2], x23.x, xdN); xdN = fma(wiN[4*w+3], x23.y, xdN);
      }
      // quad reduce over q (lanes xor 1, 2)
      hdR += __shfl_xor(hdR, 1, 64); hdR += __shfl_xor(hdR, 2, 64);
      hdZ += __shfl_xor(hdZ, 1, 64); hdZ += __shfl_xor(hdZ, 2, 64);
      hdN += __shfl_xor(hdN, 1, 64); hdN += __shfl_xor(hdN, 2, 64);
      xdR += __shfl_xor(xdR, 1, 64); xdR += __shfl_xor(xdR, 2, 64);
      xdZ += __shfl_xor(xdZ, 1, 64); xdZ += __shfl_xor(xdZ, 2, 64);
      xdN += __shfl_xor(xdN, 1, 64); xdN += __shfl_xor(xdN, 2, 64);

      if (q == 0){
        psh[0][j] = hdR + xdR;     // r pre-activation (biases inside)
        psh[1][j] = hdZ + xdZ;     // z pre-activation
        psh[2][j] = xdN;           // x-side n (incl b_ih_n)
        psh[3][j] = hdN;           // h-side n (incl b_hh_n)
      }
      __syncthreads();             // b1: pre-activations published

      // ---- gate phase: wave 0 only (lane l <-> row l), issued ONCE ----
      if (tid < 64){
        double aR = psh[0][tid];
        double aZ = psh[1][tid];
        double xnv = psh[2][tid];
        double hnv = psh[3][tid];
        double r  = rcp_nr(1.0 + exp_d(-aR));
        double z  = rcp_nr(1.0 + exp_d(-aZ));
        double yn = xnv + r*hnv;
        double nnv = 1.0 - 2.0*rcp_nr(exp_d(2.0*yn) + 1.0);
        h = (1.0 - z)*nnv + z*h;
        hsh[tid + 2*(tid>>4)] = h;
      } else if (tid < 128){
        // wave 1: stage x[t+1] from the register pipeline
        float xs = (u==0) ? xr0 : (u==1) ? xr1 : (u==2) ? xr2 : xr3;
        xsh[l2 + 2*(l2>>4)] = (double)xs;
      }
      __syncthreads();             // b2: h[t+1], x[t+1] visible
    }
    // rotate prefetch registers (next superstep's values, long complete)
    xr0 = xn0; xr1 = xn1; xr2 = xn2; xr3 = xn3;
  }

  if (tid < 64){
    qout[(size_t)(TSTEPS-1)*NB*64] = (_Float16)(float)h;   // final store
    out_state[(size_t)(g*512 + n)*64 + tid] = (float)h;
  }
}

// ---------------------------------------------------------------------------
// Attention + output projection (unchanged — output 0 passed with it).
// One wave per (t,b) tile; mfma_f32_32x32x16_f16; f32 output.
// ---------------------------------------------------------------------------
__global__ __launch_bounds__(64) void attn(
    const _Float16* __restrict__ qkv,        // [3,500,512,64] f16
    const float* __restrict__ w_o,           // [64,64] f32
    const float* __restrict__ b_o,           // [64] f32
    float* __restrict__ out)                 // [500,16,32,64] f32
{
  __shared__ __align__(16) _Float16 Qs[32*72];
  __shared__ __align__(16) _Float16 Ks[32*72];
  __shared__ __align__(16) _Float16 Vt[64*40];
  __shared__ __align__(16) _Float16 Wm[32*40];
  __shared__ __align__(16) _Float16 wols[64*72];
  __shared__ float bo[64];

  const int lane = threadIdx.x;
  const int t = blockIdx.x >> 4;
  const int b = blockIdx.x & 15;
  const size_t base    = ((size_t)t*NB + b*32)*64;
  const size_t gstride = (size_t)TSTEPS*NB*64;

  #pragma unroll
  for (int it=0; it<4; ++it){
    int idx = it*64 + lane;
    int f = idx >> 3, ko = (idx & 7)*8;
    *(f16x8*)&Qs[f*72+ko] = *(const f16x8*)&qkv[base + (size_t)f*64 + ko];
    *(f16x8*)&Ks[f*72+ko] = *(const f16x8*)&qkv[gstride + base + (size_t)f*64 + ko];
  }
  #pragma unroll
  for (int it=0; it<32; ++it){
    int idx = it*64 + lane;
    int f = idx >> 6, hh = idx & 63;
    Vt[hh*40 + f] = qkv[2*gstride + base + (size_t)f*64 + hh];
  }
  #pragma unroll
  for (int it=0; it<32; ++it){
    int idx = it*64 + lane;
    int c = idx >> 5, hp = (idx & 31)*2;
    float2 u = *(const float2*)(w_o + c*64 + hp);
    wols[c*72 + hp]     = (_Float16)u.x;
    wols[c*72 + hp + 1] = (_Float16)u.y;
  }
  bo[lane] = b_o[lane];

  const int m  = lane & 31;
  const int hk = (lane >> 5) * 8;
  const int rbase = (lane >> 5) * 4;

  // ---- W = Q @ K^T ----
  f32x16 accW;
  #pragma unroll
  for (int i=0;i<16;++i) accW[i]=0.f;
  #pragma unroll
  for (int kb=0; kb<4; ++kb){
    f16x8 a  = *(const f16x8*)&Qs[m*72 + kb*16 + hk];
    f16x8 bb = *(const f16x8*)&Ks[m*72 + kb*16 + hk];
    accW = __builtin_amdgcn_mfma_f32_32x32x16_f16(a, bb, accW, 0, 0, 0);
  }
  #pragma unroll
  for (int r=0; r<16; ++r){
    int row = (r&3) + 8*(r>>2) + rbase;
    Wm[row*40 + m] = (_Float16)accW[r];
  }

  // ---- A = W @ V ----
  f32x16 accA0, accA1;
  #pragma unroll
  for (int i=0;i<16;++i){ accA0[i]=0.f; accA1[i]=0.f; }
  #pragma unroll
  for (int kb=0; kb<2; ++kb){
    f16x8 a  = *(const f16x8*)&Wm[m*40 + kb*16 + hk];
    f16x8 b0 = *(const f16x8*)&Vt[(     m)*40 + kb*16 + hk];
    f16x8 b1 = *(const f16x8*)&Vt[(32 + m)*40 + kb*16 + hk];
    accA0 = __builtin_amdgcn_mfma_f32_32x32x16_f16(a, b0, accA0, 0, 0, 0);
    accA1 = __builtin_amdgcn_mfma_f32_32x32x16_f16(a, b1, accA1, 0, 0, 0);
  }

  // ---- softmax over f ----
  float mx0 = accA0[0], mx1 = accA1[0];
  #pragma unroll
  for (int r=1;r<16;++r){ mx0 = fmaxf(mx0, accA0[r]); mx1 = fmaxf(mx1, accA1[r]); }
  mx0 = fmaxf(mx0, __shfl_xor(mx0, 32, 64));
  mx1 = fmaxf(mx1, __shfl_xor(mx1, 32, 64));
  float s0 = 0.f, s1 = 0.f;
  #pragma unroll
  for (int r=0;r<16;++r){
    float e0 = __builtin_amdgcn_exp2f(LOG2E*(accA0[r]-mx0)); accA0[r]=e0; s0+=e0;
    float e1 = __builtin_amdgcn_exp2f(LOG2E*(accA1[r]-mx1)); accA1[r]=e1; s1+=e1;
  }
  s0 += __shfl_xor(s0, 32, 64);
  s1 += __shfl_xor(s1, 32, 64);
  float i0 = __builtin_amdgcn_rcpf(s0), i1 = __builtin_amdgcn_rcpf(s1);
  #pragma unroll
  for (int r=0;r<16;++r){
    int row = (r&3) + 8*(r>>2) + rbase;
    Qs[row*72 + m]      = (_Float16)(accA0[r]*i0);
    Qs[row*72 + 32 + m] = (_Float16)(accA1[r]*i1);
  }

  // ---- O = P @ w_o^T + b_o ----
  f32x16 accO0, accO1;
  #pragma unroll
  for (int i=0;i<16;++i){ accO0[i]=0.f; accO1[i]=0.f; }
  #pragma unroll
  for (int kb=0; kb<4; ++kb){
    f16x8 a  = *(const f16x8*)&Qs[m*72 + kb*16 + hk];
    f16x8 b0 = *(const f16x8*)&wols[(     m)*72 + kb*16 + hk];
    f16x8 b1 = *(const f16x8*)&wols[(32 + m)*72 + kb*16 + hk];
    accO0 = __builtin_amdgcn_mfma_f32_32x32x16_f16(a, b0, accO0, 0, 0, 0);
    accO1 = __builtin_amdgcn_mfma_f32_32x32x16_f16(a, b1, accO1, 0, 0, 0);
  }
  const size_t obase = ((size_t)t*16 + b)*2048;
  #pragma unroll
  for (int r=0;r<16;++r){
    int row = (r&3) + 8*(r>>2) + rbase;
    out[obase + row*64 + m]      = accO0[r] + bo[m];
    out[obase + row*64 + 32 + m] = accO1[r] + bo[32+m];
  }
}

// ---------------------------------------------------------------------------
extern "C" void kernel_launch(void* const* d_in, const int* in_sizes, int n_in,
                              void* d_out, int out_size, void* d_ws, size_t ws_size,
                              hipStream_t stream)
{
  const float* x  = (const float*)d_in[0];
  const float* st = (const float*)d_in[1];
  _Float16* qkv = (_Float16*)d_ws;   // 98,304,000 B (fits)
  float* out = (float*)d_out;
  float* out_state = out + (size_t)16384000;

  gru_f64<<<dim3(1536), dim3(256), 0, stream>>>(
    x, st,
    (const float*)d_in[2],  (const float*)d_in[3],
    (const float*)d_in[4],  (const float*)d_in[5],
    (const float*)d_in[6],  (const float*)d_in[7],
    (const float*)d_in[8],  (const float*)d_in[9],
    (const float*)d_in[10], (const float*)d_in[11],
    (const float*)d_in[12], (const float*)d_in[13],
    qkv, out_state);

  attn<<<dim3(8000), dim3(64), 0, stream>>>(
    qkv, (const float*)d_in[14], (const float*)d_in[15], out);
}